// Round 4
// baseline (1553.662 us; speedup 1.0000x reference)
//
#include <hip/hip_runtime.h>
#include <math.h>

#define L_  28
#define H_  1024
#define NH_ 8
#define KVH_ 4
#define HD_ 128
#define I_  3072
#define VC_ 4096
#define B_  4
#define S_  512
#define EPS_ 1e-6f

// ---- workspace layout (float offsets) ----
#define WS_H    0                       // [4][1024] live residual (atomic target)
#define WS_QKVB 4096                    // [4][2048] dense qkv (atomic target)
#define WS_ATTO 12288                   // [16 bg][2 r][16 c][128]
#define WS_ATML 77824                   // [16 bg][2 r][16 c][2]
#define WS_GUPB 78848                   // [4][6144] dense gate/up (atomic target)
// end: 103424 floats = 414 KB

__device__ __forceinline__ float wave_reduce_sum(float v) {
    #pragma unroll
    for (int off = 32; off; off >>= 1) v += __shfl_down(v, off);
    return v;
}
__device__ __forceinline__ float wave_reduce_max(float v) {
    #pragma unroll
    for (int off = 32; off; off >>= 1) v = fmaxf(v, __shfl_down(v, off));
    return v;
}

// block=256: reduce 4 per-batch sums across the block. red = LDS float[16].
__device__ __forceinline__ void reduce4(float ss[4], float* red, int t) {
    int lane = t & 63, wv = t >> 6;
    #pragma unroll
    for (int b = 0; b < 4; b++) {
        float v = wave_reduce_sum(ss[b]);
        if (lane == 0) red[b * 4 + wv] = v;
    }
    __syncthreads();
    #pragma unroll
    for (int b = 0; b < 4; b++)
        ss[b] = red[b * 4] + red[b * 4 + 1] + red[b * 4 + 2] + red[b * 4 + 3];
    __syncthreads();
}

// ---------------- embed (+ zero logits & qkvb) ----------------
__global__ __launch_bounds__(256) void k_embed(
    const int* __restrict__ cb0, const int* __restrict__ cb1,
    const float* __restrict__ trail, const float* __restrict__ cb0e,
    const float* __restrict__ cpe, float* __restrict__ hcur,
    float* __restrict__ qkvb, float* __restrict__ logits)
{
    int idx = blockIdx.x * 256 + threadIdx.x;   // 0..4095
    int b = idx >> 10, i = idx & 1023;
    float v = cb0e[(size_t)cb0[b] * 1024 + i] + trail[idx];
    #pragma unroll
    for (int j = 0; j < 15; j++)
        v += cpe[((size_t)j * 4096 + cb1[b * 15 + j]) * 1024 + i];
    hcur[idx] = v;
    float4 z = {0.f, 0.f, 0.f, 0.f};
    *(float4*)(logits + (size_t)idx * 4) = z;       // 16384 floats
    qkvb[idx * 2] = 0.f; qkvb[idx * 2 + 1] = 0.f;   // 8192 floats
}

// ---------------- GEMV core (atomic-out, weight preload, prologue lambda) ----------------
// block = 256 thr (4 waves); 256 cols; RPW*4 rows. xsl: LDS [RPW*4][4].
// out[b*outstride + outcol0 + col] += dot.
template<int RPW, typename F>
__device__ __forceinline__ void gemv_atomic(
    const float* __restrict__ W, int ldw, int wcol0, int k0,
    const float* __restrict__ xsl, float4* __restrict__ accbuf,
    float* __restrict__ outp, int outstride, int outcol0, F&& prologue)
{
    const int t = threadIdx.x;
    const int wv = t >> 6, lane = t & 63;
    const float* Wp = W + (size_t)(k0 + wv * RPW) * ldw + wcol0 + lane * 4;
    float4 wreg[RPW];
    #pragma unroll
    for (int i = 0; i < RPW; i++) wreg[i] = *(const float4*)(Wp + (size_t)i * ldw);
    prologue();   // fills xsl; must end with __syncthreads()
    const float4* xs4 = (const float4*)xsl;
    float4 a0 = {0,0,0,0}, a1 = {0,0,0,0}, a2 = {0,0,0,0}, a3 = {0,0,0,0};
    #pragma unroll
    for (int i = 0; i < RPW; i++) {
        float4 w4 = wreg[i];
        float4 xb = xs4[wv * RPW + i];
        a0.x += w4.x * xb.x; a0.y += w4.y * xb.x; a0.z += w4.z * xb.x; a0.w += w4.w * xb.x;
        a1.x += w4.x * xb.y; a1.y += w4.y * xb.y; a1.z += w4.z * xb.y; a1.w += w4.w * xb.y;
        a2.x += w4.x * xb.z; a2.y += w4.y * xb.z; a2.z += w4.z * xb.z; a2.w += w4.w * xb.z;
        a3.x += w4.x * xb.w; a3.y += w4.y * xb.w; a3.z += w4.z * xb.w; a3.w += w4.w * xb.w;
    }
    accbuf[(wv * 64 + lane) * 4 + 0] = a0;
    accbuf[(wv * 64 + lane) * 4 + 1] = a1;
    accbuf[(wv * 64 + lane) * 4 + 2] = a2;
    accbuf[(wv * 64 + lane) * 4 + 3] = a3;
    __syncthreads();
    const int l2 = t >> 2, b2 = t & 3;
    float4 s = {0,0,0,0};
    #pragma unroll
    for (int w = 0; w < 4; w++) {
        float4 sv = accbuf[(w * 64 + l2) * 4 + b2];
        s.x += sv.x; s.y += sv.y; s.z += sv.z; s.w += sv.w;
    }
    float* op = outp + (size_t)b2 * outstride + outcol0 + l2 * 4;
    unsafeAtomicAdd(op + 0, s.x);
    unsafeAtomicAdd(op + 1, s.y);
    unsafeAtomicAdd(op + 2, s.z);
    unsafeAtomicAdd(op + 3, s.w);
}

// ---------------- qkv GEMV (fused rmsnorm1 prologue): grid (8, 32) ----------------
__global__ __launch_bounds__(256) void k_qkv(
    const float* __restrict__ hcur, const float* __restrict__ ln1,
    const float* __restrict__ Wq, const float* __restrict__ Wk,
    const float* __restrict__ Wv, float* __restrict__ qkvb)
{
    __shared__ float xsl[128];
    __shared__ float4 accbuf[1024];
    __shared__ float red[16];
    const int t = threadIdx.x;
    const int ks = blockIdx.y, k0 = ks * 32, cb = blockIdx.x;
    const float* W; int ldw, wcol0, ocol0;
    if (cb < 4)      { W = Wq; ldw = 1024; wcol0 = cb * 256;      ocol0 = cb * 256; }
    else if (cb < 6) { W = Wk; ldw = 512;  wcol0 = (cb - 4) * 256; ocol0 = 1024 + (cb - 4) * 256; }
    else             { W = Wv; ldw = 512;  wcol0 = (cb - 6) * 256; ocol0 = 1536 + (cb - 6) * 256; }
    gemv_atomic<8>(W, ldw, wcol0, k0, xsl, accbuf, qkvb, 2048, ocol0, [&]() {
        float ss[4] = {0, 0, 0, 0};
        #pragma unroll
        for (int i = 0; i < 16; i++) { float v = hcur[t + 256 * i]; ss[i >> 2] += v * v; }
        reduce4(ss, red, t);
        if (t < 128) {
            int kk = t & 31, b = t >> 5;
            float rms = rsqrtf(ss[b] * (1.f / 1024.f) + EPS_);
            xsl[kk * 4 + b] = hcur[b * 1024 + k0 + kk] * rms * ln1[k0 + kk];
        }
        __syncthreads();
    });
}

// ---------------- attention flash chunk: grid (16 bg, 16 c), block 256 ----------------
__global__ __launch_bounds__(256) void k_attn(
    const float* __restrict__ qkvb,
    const float* __restrict__ qnw, const float* __restrict__ knw,
    const float* __restrict__ kin, const float* __restrict__ vin,
    float* __restrict__ kout, float* __restrict__ vout,
    const int* __restrict__ pos,
    float* __restrict__ opart, float* __restrict__ mlpart)
{
    __shared__ float Kl[33][129];
    __shared__ float Vl[33][129];
    __shared__ float ql[2][128];
    __shared__ float sc[2][36];
    __shared__ float red[8];

    const int t = threadIdx.x;
    const int bg = blockIdx.x, b = bg >> 2, g = bg & 3;
    const int c = blockIdx.y;           // 0..15
    const int lane = t & 63;
    const int r = t >> 7, d = t & 127;
    const float scale = 0.088388347648318447f;  // 1/sqrt(128)

    const float posf = (float)pos[b];
    const int j = d & 63;
    const float invf = exp2f(-(float)j * 0.31143075889569021f);  // 1e6^(-j/64)
    const float ang = posf * invf;
    const float cs = cosf(ang), sn = sinf(ang);
    const int pd = (d < 64) ? d + 64 : d - 64;

    // q (dense buffer)
    float qraw = qkvb[b * 2048 + (2 * g + r) * 128 + d];
    ql[r][d] = qraw;
    float ssq = wave_reduce_sum(qraw * qraw);
    if (lane == 0) red[t >> 6] = ssq;
    __syncthreads();  // (A)
    const float rms_q = rsqrtf((red[r * 2] + red[r * 2 + 1]) * (1.f / 128.f) + EPS_);
    float qv = qraw * rms_q * qnw[d];
    float qp = ql[r][pd] * rms_q * qnw[pd];
    float qro = qv * cs + ((d < 64) ? -qp : qp) * sn;

    // new k/v: only chunk 15
    float kvraw = 0.f;
    if (c == 15) {
        const int base = (t < 128) ? (b * 2048 + 1024 + g * 128 + d)
                                   : (b * 2048 + 1536 + g * 128 + d);
        kvraw = qkvb[base];
    }
    float kss = wave_reduce_sum((t < 128) ? kvraw * kvraw : 0.f);
    __syncthreads();  // (B)
    ql[r][d] = qro;
    if (lane == 0 && t < 128) red[t >> 6] = kss;
    if (c == 15) { if (t < 128) Kl[32][d] = kvraw; else Vl[32][d] = kvraw; }
    __syncthreads();  // (C)
    float newkv = 0.f;
    if (c == 15) {
        if (t < 128) {
            const float rms_k = rsqrtf((red[0] + red[1]) * (1.f / 128.f) + EPS_);
            float kv_ = Kl[32][d] * rms_k * knw[d];
            float kp  = Kl[32][pd] * rms_k * knw[pd];
            newkv = kv_ * cs + ((d < 64) ? -kp : kp) * sn;
        } else {
            newkv = Vl[32][d];
        }
    }
    __syncthreads();  // (D)
    const size_t out_bg = (size_t)bg * (513 * 128);
    if (c == 15) {
        if (t < 128) { Kl[32][d] = newkv; kout[out_bg + 512 * 128 + d] = newkv; }
        else         { Vl[32][d] = newkv; vout[out_bg + 512 * 128 + d] = newkv; }
    }

    // KV tile (32 keys) load into LDS + copy to output cache (float4)
    const size_t in_bg = (size_t)bg * (512 * 128);
    const int s0 = c * 32;
    #pragma unroll
    for (int i = 0; i < 4; i++) {
        int f4 = i * 256 + t;           // 0..1023 float4s
        int row = f4 >> 5, d0 = (f4 & 31) * 4;
        float4 k4 = *(const float4*)(kin + in_bg + (size_t)(s0 + row) * 128 + d0);
        float4 v4 = *(const float4*)(vin + in_bg + (size_t)(s0 + row) * 128 + d0);
        Kl[row][d0] = k4.x; Kl[row][d0 + 1] = k4.y; Kl[row][d0 + 2] = k4.z; Kl[row][d0 + 3] = k4.w;
        Vl[row][d0] = v4.x; Vl[row][d0 + 1] = v4.y; Vl[row][d0 + 2] = v4.z; Vl[row][d0 + 3] = v4.w;
        *(float4*)(kout + out_bg + (size_t)(s0 + row) * 128 + d0) = k4;
        *(float4*)(vout + out_bg + (size_t)(s0 + row) * 128 + d0) = v4;
    }
    __syncthreads();  // (E)

    // scores
    const int nk = (c == 15) ? 33 : 32;
    const int si = d;
    float sv = -1e30f;
    if (si < nk) {
        float a = 0.f;
        #pragma unroll 8
        for (int dd = 0; dd < 128; dd++) a += ql[r][dd] * Kl[si][dd];
        sv = a * scale;
    }
    float mv = wave_reduce_max(sv);
    if (lane == 0) red[t >> 6] = mv;
    __syncthreads();
    const float m = fmaxf(red[r * 2], red[r * 2 + 1]);
    float p = (si < nk) ? expf(sv - m) : 0.f;
    if (si < nk) sc[r][si] = p;
    float lsum = wave_reduce_sum(p);
    __syncthreads();
    if (lane == 0) red[t >> 6] = lsum;
    __syncthreads();
    const float lr = red[r * 2] + red[r * 2 + 1];
    if (d == 0) {
        mlpart[(size_t)((bg * 2 + r) * 16 + c) * 2 + 0] = m;
        mlpart[(size_t)((bg * 2 + r) * 16 + c) * 2 + 1] = lr;
    }
    float o = 0.f;
    for (int s2 = 0; s2 < nk; s2++) o += sc[r][s2] * Vl[s2][d];
    opart[(size_t)((bg * 2 + r) * 16 + c) * 128 + d] = o;
}

// ---------------- o-proj GEMV (fused flash combine; atomic into hcur; zero gupb): grid (4, 32) ----------------
__global__ __launch_bounds__(256) void k_oproj(
    const float* __restrict__ atto, const float* __restrict__ atml,
    const float* __restrict__ Wo_l, float* __restrict__ hcur,
    float* __restrict__ gupb)
{
    __shared__ float xsl[128];
    __shared__ float4 accbuf[1024];
    const int t = threadIdx.x;
    const int ks = blockIdx.y, k0 = ks * 32, cb = blockIdx.x;
    gemv_atomic<8>(Wo_l, 1024, cb * 256, k0, xsl, accbuf, hcur, 1024, cb * 256, [&]() {
        const int bl = ks * 4 + cb;        // 0..127
        if (t < 192) gupb[bl * 192 + t] = 0.f;   // 128*192 = 24576
        if (t < 128) {
            const int kk = t & 31, b = t >> 5;
            const int nrow = k0 + kk;
            const int head = nrow >> 7, dh = nrow & 127;
            const int g = head >> 1, rr = head & 1;
            const size_t base = (size_t)((b * 4 + g) * 2 + rr) * 16;
            float mc[16], lc[16], M = -1e30f;
            #pragma unroll
            for (int cc = 0; cc < 16; cc++) {
                mc[cc] = atml[(base + cc) * 2];
                lc[cc] = atml[(base + cc) * 2 + 1];
                M = fmaxf(M, mc[cc]);
            }
            float Ls = 0.f, o = 0.f;
            #pragma unroll
            for (int cc = 0; cc < 16; cc++) {
                float wch = expf(mc[cc] - M);
                Ls += lc[cc] * wch;
                o += atto[(base + cc) * 128 + dh] * wch;
            }
            xsl[kk * 4 + b] = o / Ls;
        }
        __syncthreads();
    });
}

// ---------------- gate/up GEMV (fused rmsnorm2 prologue): grid (24, 32) ----------------
__global__ __launch_bounds__(256) void k_gateup(
    const float* __restrict__ hcur, const float* __restrict__ ln2,
    const float* __restrict__ Wg_l, const float* __restrict__ Wu_l,
    float* __restrict__ gupb)
{
    __shared__ float xsl[128];
    __shared__ float4 accbuf[1024];
    __shared__ float red[16];
    const int t = threadIdx.x;
    const int ks = blockIdx.y, k0 = ks * 32, cb = blockIdx.x;
    const float* W; int wcol0, ocol0;
    if (cb < 12) { W = Wg_l; wcol0 = cb * 256;        ocol0 = cb * 256; }
    else         { W = Wu_l; wcol0 = (cb - 12) * 256; ocol0 = 3072 + (cb - 12) * 256; }
    gemv_atomic<8>(W, 3072, wcol0, k0, xsl, accbuf, gupb, 6144, ocol0, [&]() {
        float ss[4] = {0, 0, 0, 0};
        #pragma unroll
        for (int i = 0; i < 16; i++) { float v = hcur[t + 256 * i]; ss[i >> 2] += v * v; }
        reduce4(ss, red, t);
        if (t < 128) {
            int kk = t & 31, b = t >> 5;
            float rms = rsqrtf(ss[b] * (1.f / 1024.f) + EPS_);
            xsl[kk * 4 + b] = hcur[b * 1024 + k0 + kk] * rms * ln2[k0 + kk];
        }
        __syncthreads();
    });
}

// ---------------- down GEMV (fused SiLU prologue; atomic into hcur; zero qkvb): grid (4, 96) ----------------
__global__ __launch_bounds__(256) void k_down(
    const float* __restrict__ gupb, const float* __restrict__ Wd_l,
    float* __restrict__ hcur, float* __restrict__ qkvb)
{
    __shared__ float xsl[128];
    __shared__ float4 accbuf[1024];
    const int t = threadIdx.x;
    const int ks = blockIdx.y, k0 = ks * 32, cb = blockIdx.x;
    gemv_atomic<8>(Wd_l, 1024, cb * 256, k0, xsl, accbuf, hcur, 1024, cb * 256, [&]() {
        const int bl = ks * 4 + cb;        // 0..383
        if (bl < 128 && t < 64) qkvb[bl * 64 + t] = 0.f;   // 128*64 = 8192
        if (t < 128) {
            int kk = t & 31, b = t >> 5;
            float gg = gupb[b * 6144 + k0 + kk];
            float uu = gupb[b * 6144 + 3072 + k0 + kk];
            xsl[kk * 4 + b] = gg / (1.f + expf(-gg)) * uu;
        }
        __syncthreads();
    });
}

// ---------------- head GEMV (fused final norm; atomic into logits; writes past): grid (16, 32) ----------------
__global__ __launch_bounds__(256) void k_head(
    const float* __restrict__ hcur, const float* __restrict__ normw,
    const float* __restrict__ headw, float* __restrict__ logits,
    float* __restrict__ past)
{
    __shared__ float xsl[128];
    __shared__ float4 accbuf[1024];
    __shared__ float red[16];
    const int t = threadIdx.x;
    const int ks = blockIdx.y, k0 = ks * 32, cb = blockIdx.x;
    gemv_atomic<8>(headw, 4096, cb * 256, k0, xsl, accbuf, logits, 4096, cb * 256, [&]() {
        float ss[4] = {0, 0, 0, 0};
        #pragma unroll
        for (int i = 0; i < 16; i++) { float v = hcur[t + 256 * i]; ss[i >> 2] += v * v; }
        reduce4(ss, red, t);
        if (t < 128) {
            int kk = t & 31, b = t >> 5;
            float rms = rsqrtf(ss[b] * (1.f / 1024.f) + EPS_);
            float x = hcur[b * 1024 + k0 + kk] * rms * normw[k0 + kk];
            xsl[kk * 4 + b] = x;
            if (cb == 0) past[b * 1024 + k0 + kk] = x;
        }
        __syncthreads();
    });
}

extern "C" void kernel_launch(void* const* d_in, const int* in_sizes, int n_in,
                              void* d_out, int out_size, void* d_ws, size_t ws_size,
                              hipStream_t stream)
{
    const int*   cb0   = (const int*)d_in[0];
    const int*   cb1   = (const int*)d_in[1];
    const float* trail = (const float*)d_in[2];
    const float* kvin  = (const float*)d_in[3];
    const int*   pos   = (const int*)d_in[4];
    const float* cb0e  = (const float*)d_in[5];
    const float* cpe   = (const float*)d_in[6];
    const float* Wq    = (const float*)d_in[7];
    const float* Wk    = (const float*)d_in[8];
    const float* Wv    = (const float*)d_in[9];
    const float* Wo    = (const float*)d_in[10];
    const float* qnw   = (const float*)d_in[11];
    const float* knw   = (const float*)d_in[12];
    const float* ln1   = (const float*)d_in[13];
    const float* ln2   = (const float*)d_in[14];
    const float* Wg    = (const float*)d_in[15];
    const float* Wu    = (const float*)d_in[16];
    const float* Wd    = (const float*)d_in[17];
    const float* normw = (const float*)d_in[18];
    const float* headw = (const float*)d_in[19];

    float* out    = (float*)d_out;
    float* logits = out;
    float* kvout  = out + 16384;
    float* past   = out + 16384 + (size_t)2 * L_ * B_ * KVH_ * (S_ + 1) * HD_;
    float* ws = (float*)d_ws;

    float* hcur = ws + WS_H;
    float* qkvb = ws + WS_QKVB;
    float* atto = ws + WS_ATTO;
    float* atml = ws + WS_ATML;
    float* gupb = ws + WS_GUPB;

    const size_t IN_PLANE  = (size_t)B_ * KVH_ * S_ * HD_;
    const size_t OUT_PLANE = (size_t)B_ * KVH_ * (S_ + 1) * HD_;

    k_embed<<<16, 256, 0, stream>>>(cb0, cb1, trail, cb0e, cpe, hcur, qkvb, logits);

    for (int l = 0; l < L_; l++) {
        k_qkv<<<dim3(8, 32), 256, 0, stream>>>(
            hcur, ln1 + (size_t)l * H_,
            Wq + (size_t)l * H_ * 1024, Wk + (size_t)l * H_ * 512,
            Wv + (size_t)l * H_ * 512, qkvb);
        k_attn<<<dim3(16, 16), 256, 0, stream>>>(
            qkvb, qnw + (size_t)l * HD_, knw + (size_t)l * HD_,
            kvin + (size_t)(2 * l) * IN_PLANE, kvin + (size_t)(2 * l + 1) * IN_PLANE,
            kvout + (size_t)(2 * l) * OUT_PLANE, kvout + (size_t)(2 * l + 1) * OUT_PLANE,
            pos, atto, atml);
        k_oproj<<<dim3(4, 32), 256, 0, stream>>>(
            atto, atml, Wo + (size_t)l * 1024 * H_, hcur, gupb);
        k_gateup<<<dim3(24, 32), 256, 0, stream>>>(
            hcur, ln2 + (size_t)l * H_,
            Wg + (size_t)l * H_ * I_, Wu + (size_t)l * H_ * I_, gupb);
        k_down<<<dim3(4, 96), 256, 0, stream>>>(
            gupb, Wd + (size_t)l * I_ * H_, hcur, qkvb);
    }
    k_head<<<dim3(16, 32), 256, 0, stream>>>(hcur, normw, headw, logits, past);
}

// Round 5
// 1520.415 us; speedup vs baseline: 1.0219x; 1.0219x over previous
//
#include <hip/hip_runtime.h>
#include <math.h>

#define L_  28
#define H_  1024
#define NH_ 8
#define KVH_ 4
#define HD_ 128
#define I_  3072
#define VC_ 4096
#define B_  4
#define S_  512
#define EPS_ 1e-6f

// ---- workspace layout (float offsets) ----
#define WS_H     0            // [4][1024] residual
#define WS_SSQ1P 4096         // [16][4] ssq partials for ln1/final (written by down-fold / embed)
#define WS_SSQ2P 4160         // [16][4] ssq partials for ln2 (written by oproj-fold)
#define WS_CNT   4224         // 24 ints (oproj 0..3, down 4..7, head 8..23)
#define WS_QKVP  4256         // [32][4][2048]
#define WS_ATTO  266400       // [16 bg][2 r][16 c][128]
#define WS_ATML  331936       // [16 bg][2 r][16 c][2]
#define WS_OPP   333984       // [32][4][1024]
#define WS_GUP   465056       // [32][4][6144]
#define WS_DWP   1251488      // [48][4][1024]
#define WS_HDP   1448096      // [32][4][4096]
// end: 1972384 floats = 7.9 MB

__device__ __forceinline__ float wave_reduce_sum(float v) {
    #pragma unroll
    for (int off = 32; off; off >>= 1) v += __shfl_down(v, off);
    return v;
}
__device__ __forceinline__ float wave_reduce_max(float v) {
    #pragma unroll
    for (int off = 32; off; off >>= 1) v = fmaxf(v, __shfl_down(v, off));
    return v;
}

// ---------------- embed: h + ssq1 partials + zero counters ----------------
// grid 16 (b*4+q), block 256
__global__ __launch_bounds__(256) void k_embed(
    const int* __restrict__ cb0, const int* __restrict__ cb1,
    const float* __restrict__ trail, const float* __restrict__ cb0e,
    const float* __restrict__ cpe, float* __restrict__ h,
    float* __restrict__ ssq1p, int* __restrict__ cnt)
{
    const int x = blockIdx.x, t = threadIdx.x;
    const int b = x >> 2, q = x & 3;
    const int i = q * 256 + t;
    float v = cb0e[(size_t)cb0[b] * 1024 + i] + trail[b * 1024 + i];
    #pragma unroll
    for (int j = 0; j < 15; j++)
        v += cpe[((size_t)j * 4096 + cb1[b * 15 + j]) * 1024 + i];
    h[b * 1024 + i] = v;
    float s = wave_reduce_sum(v * v);
    if ((t & 63) == 0) ssq1p[(q * 4 + (t >> 6)) * 4 + b] = s;   // sub = wave = 64-col slice
    if (x == 0 && t < 24) cnt[t] = 0;
}

// ---------------- GEMV core: block = 256 thr (4 waves), 256 cols, RPC rows ----------------
template<int RPC, int NTOT>
__device__ __forceinline__ void gemv_tail(
    const float* __restrict__ W, int ldw, int wcol0, int k0,
    const float* __restrict__ xsl, float4* __restrict__ accbuf,
    float* __restrict__ pp, int colblk, int ks)
{
    const int t = threadIdx.x;
    const int wv = t >> 6, lane = t & 63;
    constexpr int RPW = RPC / 4;                  // rows per wave
    const float4* xs4 = (const float4*)xsl;
    float4 a0 = {0,0,0,0}, a1 = {0,0,0,0}, a2 = {0,0,0,0}, a3 = {0,0,0,0};
    const float* Wp = W + (size_t)(k0 + wv * RPW) * ldw + wcol0 + lane * 4;
    #pragma unroll 8
    for (int i = 0; i < RPW; i++) {
        float4 wvv = *(const float4*)(Wp + (size_t)i * ldw);
        float4 xb = xs4[wv * RPW + i];
        a0.x += wvv.x * xb.x; a0.y += wvv.y * xb.x; a0.z += wvv.z * xb.x; a0.w += wvv.w * xb.x;
        a1.x += wvv.x * xb.y; a1.y += wvv.y * xb.y; a1.z += wvv.z * xb.y; a1.w += wvv.w * xb.y;
        a2.x += wvv.x * xb.z; a2.y += wvv.y * xb.z; a2.z += wvv.z * xb.z; a2.w += wvv.w * xb.z;
        a3.x += wvv.x * xb.w; a3.y += wvv.y * xb.w; a3.z += wvv.z * xb.w; a3.w += wvv.w * xb.w;
    }
    accbuf[(wv * 64 + lane) * 4 + 0] = a0;
    accbuf[(wv * 64 + lane) * 4 + 1] = a1;
    accbuf[(wv * 64 + lane) * 4 + 2] = a2;
    accbuf[(wv * 64 + lane) * 4 + 3] = a3;
    __syncthreads();
    const int l2 = t >> 2, b2 = t & 3;
    float4 s0 = accbuf[(0 * 64 + l2) * 4 + b2];
    float4 s1 = accbuf[(1 * 64 + l2) * 4 + b2];
    float4 s2 = accbuf[(2 * 64 + l2) * 4 + b2];
    float4 s3 = accbuf[(3 * 64 + l2) * 4 + b2];
    float4 s;
    s.x = s0.x + s1.x + s2.x + s3.x;
    s.y = s0.y + s1.y + s2.y + s3.y;
    s.z = s0.z + s1.z + s2.z + s3.z;
    s.w = s0.w + s1.w + s2.w + s3.w;
    *(float4*)(pp + ((size_t)ks * 4 + b2) * NTOT + colblk * 256 + l2 * 4) = s;
}

// ---------------- counter-based split-K fold ----------------
// All blocks of a (cb) group call this after storing partials. Last 4 arrivals
// each fold a 64-col subslice: out[b*NT+col] = (ADD_H ? h : 0) + sum of NCH chunks.
// Optionally writes per-(cb,sub) per-batch ssq partials (deterministic sums).
template<int NCH, bool ADD_H>
__device__ __forceinline__ void split_fold(
    const float* __restrict__ part, float* __restrict__ hbuf,
    float* __restrict__ outbuf, int NT,
    float* __restrict__ ssqp, int* __restrict__ cntp, int cb)
{
    __shared__ int oldsh;
    __shared__ float tmp[16];
    const int t = threadIdx.x;
    __syncthreads();   // all partial stores drained (vmcnt 0 at barrier)
    if (t == 0) {
        __threadfence();                    // release: make our stores device-visible
        oldsh = atomicAdd(cntp, 1);
        __threadfence();                    // acquire: invalidate stale L2 before fold reads
    }
    __syncthreads();
    const int old = oldsh;
    if (old < NCH - 4) return;
    const int sub = old - (NCH - 4);        // 0..3
    const int col = cb * 256 + sub * 64 + (t >> 2);
    const int b = t & 3;
    float acc = ADD_H ? hbuf[b * 1024 + col] : 0.f;
    #pragma unroll 8
    for (int c = 0; c < NCH; c++) acc += part[(size_t)(c * 4 + b) * NT + col];
    outbuf[(size_t)b * NT + col] = acc;
    if (ssqp) {
        float v = acc * acc;
        #pragma unroll
        for (int off = 32; off >= 4; off >>= 1) v += __shfl_down(v, off);  // b-preserving
        if ((t & 63) < 4) tmp[(t >> 6) * 4 + (t & 3)] = v;
        __syncthreads();
        if (t < 4) ssqp[(cb * 4 + sub) * 4 + t] = tmp[t] + tmp[4 + t] + tmp[8 + t] + tmp[12 + t];
    }
    if (old == NCH - 1 && t == 0) *cntp = 0;   // reset for next layer
}

// ---------------- qkv GEMV (rmsnorm1 prologue from ssq partials): grid (8, 32) ----------------
__global__ __launch_bounds__(256) void k_qkv(
    const float* __restrict__ h, const float* __restrict__ ssq1p,
    const float* __restrict__ ln1,
    const float* __restrict__ Wq, const float* __restrict__ Wk,
    const float* __restrict__ Wv, float* __restrict__ qkvp)
{
    __shared__ float xsl[128];
    __shared__ float4 accbuf[1024];
    const int t = threadIdx.x;
    const int ks = blockIdx.y, k0 = ks * 32, cb = blockIdx.x;
    if (t < 128) {
        const int kk = t & 31, b = t >> 5;
        float ssq = 0.f;
        #pragma unroll
        for (int i = 0; i < 16; i++) ssq += ssq1p[i * 4 + b];
        const float rms = rsqrtf(ssq * (1.f / 1024.f) + EPS_);
        xsl[kk * 4 + b] = h[b * 1024 + k0 + kk] * rms * ln1[k0 + kk];
    }
    __syncthreads();
    const float* W; int ldw, wcol0;
    if (cb < 4)      { W = Wq; ldw = 1024; wcol0 = cb * 256; }
    else if (cb < 6) { W = Wk; ldw = 512;  wcol0 = (cb - 4) * 256; }
    else             { W = Wv; ldw = 512;  wcol0 = (cb - 6) * 256; }
    gemv_tail<32, 2048>(W, ldw, wcol0, k0, xsl, accbuf, qkvp, cb, ks);
}

// ---------------- attention flash chunk: grid (16 bg, 16 c), block 256 ----------------
__global__ __launch_bounds__(256) void k_attn(
    const float* __restrict__ qkvp,
    const float* __restrict__ qnw, const float* __restrict__ knw,
    const float* __restrict__ kin, const float* __restrict__ vin,
    float* __restrict__ kout, float* __restrict__ vout,
    const int* __restrict__ pos,
    float* __restrict__ opart, float* __restrict__ mlpart)
{
    __shared__ float Kl[33][129];
    __shared__ float Vl[33][129];
    __shared__ float ql[2][128];
    __shared__ float sc[2][36];
    __shared__ float red[8];

    const int t = threadIdx.x;
    const int bg = blockIdx.x, b = bg >> 2, g = bg & 3;
    const int c = blockIdx.y;           // 0..15
    const int lane = t & 63;
    const int r = t >> 7, d = t & 127;
    const float scale = 0.088388347648318447f;  // 1/sqrt(128)

    const float posf = (float)pos[b];
    const int j = d & 63;
    const float invf = exp2f(-(float)j * 0.31143075889569021f);  // 1e6^(-j/64)
    const float ang = posf * invf;
    const float cs = cosf(ang), sn = sinf(ang);
    const int pd = (d < 64) ? d + 64 : d - 64;

    // q: reduce 32 split-K chunks
    float qraw = 0.f;
    {
        const int n = (2 * g + r) * 128 + d;
        #pragma unroll
        for (int cc = 0; cc < 32; cc++) qraw += qkvp[((size_t)cc * 4 + b) * 2048 + n];
    }
    ql[r][d] = qraw;
    float ssq = wave_reduce_sum(qraw * qraw);
    if (lane == 0) red[t >> 6] = ssq;
    __syncthreads();  // (A)
    const float rms_q = rsqrtf((red[r * 2] + red[r * 2 + 1]) * (1.f / 128.f) + EPS_);
    float qv = qraw * rms_q * qnw[d];
    float qp = ql[r][pd] * rms_q * qnw[pd];
    float qro = qv * cs + ((d < 64) ? -qp : qp) * sn;

    // new k/v: only chunk 15
    float kvraw = 0.f;
    if (c == 15) {
        const int base = (t < 128) ? (1024 + g * 128 + d) : (1536 + g * 128 + d);
        #pragma unroll
        for (int cc = 0; cc < 32; cc++) kvraw += qkvp[((size_t)cc * 4 + b) * 2048 + base];
    }
    float kss = wave_reduce_sum((t < 128) ? kvraw * kvraw : 0.f);
    __syncthreads();  // (B)
    ql[r][d] = qro;
    if (lane == 0 && t < 128) red[t >> 6] = kss;
    if (c == 15) { if (t < 128) Kl[32][d] = kvraw; else Vl[32][d] = kvraw; }
    __syncthreads();  // (C)
    float newkv = 0.f;
    if (c == 15) {
        if (t < 128) {
            const float rms_k = rsqrtf((red[0] + red[1]) * (1.f / 128.f) + EPS_);
            float kv_ = Kl[32][d] * rms_k * knw[d];
            float kp  = Kl[32][pd] * rms_k * knw[pd];
            newkv = kv_ * cs + ((d < 64) ? -kp : kp) * sn;
        } else {
            newkv = Vl[32][d];
        }
    }
    __syncthreads();  // (D)
    const size_t out_bg = (size_t)bg * (513 * 128);
    if (c == 15) {
        if (t < 128) { Kl[32][d] = newkv; kout[out_bg + 512 * 128 + d] = newkv; }
        else         { Vl[32][d] = newkv; vout[out_bg + 512 * 128 + d] = newkv; }
    }

    // KV tile (32 keys) load into LDS + copy to output cache (float4)
    const size_t in_bg = (size_t)bg * (512 * 128);
    const int s0 = c * 32;
    #pragma unroll
    for (int i = 0; i < 4; i++) {
        int f4 = i * 256 + t;           // 0..1023 float4s
        int row = f4 >> 5, d0 = (f4 & 31) * 4;
        float4 k4 = *(const float4*)(kin + in_bg + (size_t)(s0 + row) * 128 + d0);
        float4 v4 = *(const float4*)(vin + in_bg + (size_t)(s0 + row) * 128 + d0);
        Kl[row][d0] = k4.x; Kl[row][d0 + 1] = k4.y; Kl[row][d0 + 2] = k4.z; Kl[row][d0 + 3] = k4.w;
        Vl[row][d0] = v4.x; Vl[row][d0 + 1] = v4.y; Vl[row][d0 + 2] = v4.z; Vl[row][d0 + 3] = v4.w;
        *(float4*)(kout + out_bg + (size_t)(s0 + row) * 128 + d0) = k4;
        *(float4*)(vout + out_bg + (size_t)(s0 + row) * 128 + d0) = v4;
    }
    __syncthreads();  // (E)

    // scores
    const int nk = (c == 15) ? 33 : 32;
    const int si = d;
    float sv = -1e30f;
    if (si < nk) {
        float a = 0.f;
        #pragma unroll 8
        for (int dd = 0; dd < 128; dd++) a += ql[r][dd] * Kl[si][dd];
        sv = a * scale;
    }
    float mv = wave_reduce_max(sv);
    if (lane == 0) red[t >> 6] = mv;
    __syncthreads();
    const float m = fmaxf(red[r * 2], red[r * 2 + 1]);
    float p = (si < nk) ? expf(sv - m) : 0.f;
    if (si < nk) sc[r][si] = p;
    float lsum = wave_reduce_sum(p);
    __syncthreads();
    if (lane == 0) red[t >> 6] = lsum;
    __syncthreads();
    const float lr = red[r * 2] + red[r * 2 + 1];
    if (d == 0) {
        mlpart[(size_t)((bg * 2 + r) * 16 + c) * 2 + 0] = m;
        mlpart[(size_t)((bg * 2 + r) * 16 + c) * 2 + 1] = lr;
    }
    float o = 0.f;
    for (int s2 = 0; s2 < nk; s2++) o += sc[r][s2] * Vl[s2][d];
    opart[(size_t)((bg * 2 + r) * 16 + c) * 128 + d] = o;
}

// ---------------- o-proj GEMV (flash combine prologue + h-fold): grid (4, 32) ----------------
__global__ __launch_bounds__(256) void k_oproj(
    const float* __restrict__ atto, const float* __restrict__ atml,
    const float* __restrict__ Wo_l, float* __restrict__ opp,
    float* __restrict__ h, float* __restrict__ ssq2p, int* __restrict__ cnt)
{
    __shared__ float xsl[128];
    __shared__ float4 accbuf[1024];
    const int t = threadIdx.x;
    const int ks = blockIdx.y, k0 = ks * 32, cb = blockIdx.x;
    if (t < 128) {
        const int kk = t & 31, b = t >> 5;
        const int nrow = k0 + kk;
        const int head = nrow >> 7, dh = nrow & 127;
        const int g = head >> 1, rr = head & 1;
        const size_t base = (size_t)((b * 4 + g) * 2 + rr) * 16;
        float mc[16], lc[16], M = -1e30f;
        #pragma unroll
        for (int cc = 0; cc < 16; cc++) {
            mc[cc] = atml[(base + cc) * 2];
            lc[cc] = atml[(base + cc) * 2 + 1];
            M = fmaxf(M, mc[cc]);
        }
        float Ls = 0.f, o = 0.f;
        #pragma unroll
        for (int cc = 0; cc < 16; cc++) {
            float wch = expf(mc[cc] - M);
            Ls += lc[cc] * wch;
            o += atto[(base + cc) * 128 + dh] * wch;
        }
        xsl[kk * 4 + b] = o / Ls;
    }
    __syncthreads();
    gemv_tail<32, 1024>(Wo_l, 1024, cb * 256, k0, xsl, accbuf, opp, cb, ks);
    split_fold<32, true>(opp, h, h, 1024, ssq2p, &cnt[cb], cb);
}

// ---------------- gate/up GEMV (rmsnorm2 prologue): grid (24, 32) ----------------
__global__ __launch_bounds__(256) void k_gateup(
    const float* __restrict__ h, const float* __restrict__ ssq2p,
    const float* __restrict__ ln2,
    const float* __restrict__ Wg_l, const float* __restrict__ Wu_l,
    float* __restrict__ gup)
{
    __shared__ float xsl[128];
    __shared__ float4 accbuf[1024];
    const int t = threadIdx.x;
    const int ks = blockIdx.y, k0 = ks * 32, cb = blockIdx.x;
    if (t < 128) {
        const int kk = t & 31, b = t >> 5;
        float ssq = 0.f;
        #pragma unroll
        for (int i = 0; i < 16; i++) ssq += ssq2p[i * 4 + b];
        const float rms = rsqrtf(ssq * (1.f / 1024.f) + EPS_);
        xsl[kk * 4 + b] = h[b * 1024 + k0 + kk] * rms * ln2[k0 + kk];
    }
    __syncthreads();
    const float* W; int wcol0;
    if (cb < 12) { W = Wg_l; wcol0 = cb * 256; }
    else         { W = Wu_l; wcol0 = (cb - 12) * 256; }
    gemv_tail<32, 6144>(W, 3072, wcol0, k0, xsl, accbuf, gup, cb, ks);
}

// ---------------- down GEMV (SiLU prologue + h-fold): grid (4, 48) ----------------
__global__ __launch_bounds__(256) void k_down(
    const float* __restrict__ gup, const float* __restrict__ Wd_l,
    float* __restrict__ dwp, float* __restrict__ h,
    float* __restrict__ ssq1p, int* __restrict__ cnt)
{
    __shared__ float xsl[256];
    __shared__ float4 accbuf[1024];
    const int t = threadIdx.x;
    const int ks = blockIdx.y, k0 = ks * 64, cb = blockIdx.x;
    {
        const int b = t >> 6, kk = t & 63;
        float gg = 0.f, uu = 0.f;
        #pragma unroll
        for (int cc = 0; cc < 32; cc++) {
            gg += gup[((size_t)cc * 4 + b) * 6144 + k0 + kk];
            uu += gup[((size_t)cc * 4 + b) * 6144 + 3072 + k0 + kk];
        }
        xsl[kk * 4 + b] = gg / (1.f + expf(-gg)) * uu;
    }
    __syncthreads();
    gemv_tail<64, 1024>(Wd_l, 1024, cb * 256, k0, xsl, accbuf, dwp, cb, ks);
    split_fold<48, true>(dwp, h, h, 1024, ssq1p, &cnt[4 + cb], cb);
}

// ---------------- head GEMV (final norm prologue + past + logits fold): grid (16, 32) ----------------
__global__ __launch_bounds__(256) void k_head(
    const float* __restrict__ h, const float* __restrict__ ssq1p,
    const float* __restrict__ normw, const float* __restrict__ headw,
    float* __restrict__ hdp, float* __restrict__ logits,
    float* __restrict__ past, int* __restrict__ cnt)
{
    __shared__ float xsl[128];
    __shared__ float4 accbuf[1024];
    const int t = threadIdx.x;
    const int ks = blockIdx.y, k0 = ks * 32, cb = blockIdx.x;
    if (t < 128) {
        const int kk = t & 31, b = t >> 5;
        float ssq = 0.f;
        #pragma unroll
        for (int i = 0; i < 16; i++) ssq += ssq1p[i * 4 + b];
        const float rms = rsqrtf(ssq * (1.f / 1024.f) + EPS_);
        float x = h[b * 1024 + k0 + kk] * rms * normw[k0 + kk];
        xsl[kk * 4 + b] = x;
        if (cb == 0) past[b * 1024 + k0 + kk] = x;
    }
    __syncthreads();
    gemv_tail<32, 4096>(headw, 4096, cb * 256, k0, xsl, accbuf, hdp, cb, ks);
    split_fold<32, false>(hdp, nullptr, logits, 4096, nullptr, &cnt[8 + cb], cb);
}

extern "C" void kernel_launch(void* const* d_in, const int* in_sizes, int n_in,
                              void* d_out, int out_size, void* d_ws, size_t ws_size,
                              hipStream_t stream)
{
    const int*   cb0   = (const int*)d_in[0];
    const int*   cb1   = (const int*)d_in[1];
    const float* trail = (const float*)d_in[2];
    const float* kvin  = (const float*)d_in[3];
    const int*   pos   = (const int*)d_in[4];
    const float* cb0e  = (const float*)d_in[5];
    const float* cpe   = (const float*)d_in[6];
    const float* Wq    = (const float*)d_in[7];
    const float* Wk    = (const float*)d_in[8];
    const float* Wv    = (const float*)d_in[9];
    const float* Wo    = (const float*)d_in[10];
    const float* qnw   = (const float*)d_in[11];
    const float* knw   = (const float*)d_in[12];
    const float* ln1   = (const float*)d_in[13];
    const float* ln2   = (const float*)d_in[14];
    const float* Wg    = (const float*)d_in[15];
    const float* Wu    = (const float*)d_in[16];
    const float* Wd    = (const float*)d_in[17];
    const float* normw = (const float*)d_in[18];
    const float* headw = (const float*)d_in[19];

    float* out    = (float*)d_out;
    float* logits = out;
    float* kvout  = out + 16384;
    float* past   = out + 16384 + (size_t)2 * L_ * B_ * KVH_ * (S_ + 1) * HD_;
    float* ws = (float*)d_ws;

    float* h     = ws + WS_H;
    float* ssq1p = ws + WS_SSQ1P;
    float* ssq2p = ws + WS_SSQ2P;
    int*   cnt   = (int*)(ws + WS_CNT);
    float* qkvp  = ws + WS_QKVP;
    float* atto  = ws + WS_ATTO;
    float* atml  = ws + WS_ATML;
    float* opp   = ws + WS_OPP;
    float* gup   = ws + WS_GUP;
    float* dwp   = ws + WS_DWP;
    float* hdp   = ws + WS_HDP;

    const size_t IN_PLANE  = (size_t)B_ * KVH_ * S_ * HD_;
    const size_t OUT_PLANE = (size_t)B_ * KVH_ * (S_ + 1) * HD_;

    k_embed<<<16, 256, 0, stream>>>(cb0, cb1, trail, cb0e, cpe, h, ssq1p, cnt);

    for (int l = 0; l < L_; l++) {
        k_qkv<<<dim3(8, 32), 256, 0, stream>>>(
            h, ssq1p, ln1 + (size_t)l * H_,
            Wq + (size_t)l * H_ * 1024, Wk + (size_t)l * H_ * 512,
            Wv + (size_t)l * H_ * 512, qkvp);
        k_attn<<<dim3(16, 16), 256, 0, stream>>>(
            qkvp, qnw + (size_t)l * HD_, knw + (size_t)l * HD_,
            kvin + (size_t)(2 * l) * IN_PLANE, kvin + (size_t)(2 * l + 1) * IN_PLANE,
            kvout + (size_t)(2 * l) * OUT_PLANE, kvout + (size_t)(2 * l + 1) * OUT_PLANE,
            pos, atto, atml);
        k_oproj<<<dim3(4, 32), 256, 0, stream>>>(
            atto, atml, Wo + (size_t)l * 1024 * H_, opp, h, ssq2p, cnt);
        k_gateup<<<dim3(24, 32), 256, 0, stream>>>(
            h, ssq2p, ln2 + (size_t)l * H_,
            Wg + (size_t)l * H_ * I_, Wu + (size_t)l * H_ * I_, gup);
        k_down<<<dim3(4, 48), 256, 0, stream>>>(
            gup, Wd + (size_t)l * I_ * H_, dwp, h, ssq1p, cnt);
    }
    k_head<<<dim3(16, 32), 256, 0, stream>>>(h, ssq1p, normw, headw, hdp, logits, past, cnt);
}

// Round 7
// 1123.947 us; speedup vs baseline: 1.3823x; 1.3527x over previous
//
#include <hip/hip_runtime.h>
#include <math.h>

#define L_  28
#define H_  1024
#define NH_ 8
#define KVH_ 4
#define HD_ 128
#define I_  3072
#define VC_ 4096
#define B_  4
#define S_  512
#define EPS_ 1e-6f

// ---- workspace layout (float offsets) ----
#define WS_H     0            // [4][1024] residual (in-place fold target)
#define WS_SSQ1  4096         // [8 slice][4 b] ssq partials (ln1 / final norm)
#define WS_SSQ2  4128         // [8 slice][4 b] ssq partials (ln2)
#define WS_QKVP  4160         // [32][4][2048]
#define WS_ATTO  266304       // [16 bg][2 r][16 c][128]
#define WS_ATML  331840       // [16 bg][2 r][16 c][2]
#define WS_OPP   332864       // [32][4][1024]
#define WS_GUP   463936       // [32][4][6144]
#define WS_DWP   1250368      // [48][4][1024]
#define WS_HDP   1446976      // [32][4][4096]
// end: 1971264 floats = 7.89 MB

__device__ __forceinline__ float wave_reduce_sum(float v) {
    #pragma unroll
    for (int off = 32; off; off >>= 1) v += __shfl_down(v, off);
    return v;
}
__device__ __forceinline__ float wave_reduce_max(float v) {
    #pragma unroll
    for (int off = 32; off; off >>= 1) v = fmaxf(v, __shfl_down(v, off));
    return v;
}

// ---------------- embed: h + ssq1 slice partials ----------------
// grid 32 (b*8+slice), block 128
__global__ __launch_bounds__(128) void k_embed(
    const int* __restrict__ cb0, const int* __restrict__ cb1,
    const float* __restrict__ trail, const float* __restrict__ cb0e,
    const float* __restrict__ cpe, float* __restrict__ h,
    float* __restrict__ ssq1)
{
    __shared__ float red[2];
    const int t = threadIdx.x;
    const int b = blockIdx.x >> 3, sl = blockIdx.x & 7;
    const int i = sl * 128 + t;
    float v = cb0e[(size_t)cb0[b] * 1024 + i] + trail[b * 1024 + i];
    #pragma unroll
    for (int j = 0; j < 15; j++)
        v += cpe[((size_t)j * 4096 + cb1[b * 15 + j]) * 1024 + i];
    h[b * 1024 + i] = v;
    float s = wave_reduce_sum(v * v);
    if ((t & 63) == 0) red[t >> 6] = s;
    __syncthreads();
    if (t == 0) ssq1[sl * 4 + b] = red[0] + red[1];
}

// ---------------- wide fold+norm: h[slice] += sum(P chunks); ssq slice partial ----------------
// grid 32 (b*8+slice), block 256
template<int P>
__global__ __launch_bounds__(256) void k_norm(
    const float* __restrict__ part, float* __restrict__ h,
    float* __restrict__ ssqp)
{
    __shared__ float red[2][128];
    __shared__ float r2[2];
    const int t = threadIdx.x;
    const int b = blockIdx.x >> 3, sl = blockIdx.x & 7;
    const int col = sl * 128 + (t & 127), half = t >> 7;
    float acc = 0.f;
    #pragma unroll 8
    for (int c = half * (P / 2); c < (half + 1) * (P / 2); c++)
        acc += part[(size_t)(c * 4 + b) * 1024 + col];
    red[half][t & 127] = acc;
    __syncthreads();
    if (half == 0) {
        float v = h[b * 1024 + col] + red[0][t] + red[1][t];
        h[b * 1024 + col] = v;
        float s = wave_reduce_sum(v * v);
        if ((t & 63) == 0) r2[t >> 6] = s;
    }
    __syncthreads();
    if (t == 0) ssqp[sl * 4 + b] = r2[0] + r2[1];
}

// ---------------- GEMV core: weight preload -> prologue -> FMA -> LDS reduce -> store ----------------
// block = 256 thr (4 waves), 256 cols, RPW*4 rows. xsl = LDS [RPW*4 rows][4 b].
template<int RPW, int NTOT, typename F>
__device__ __forceinline__ void gemv_core(
    const float* __restrict__ W, int ldw, int wcol0, int k0,
    float* __restrict__ xsl, float4* __restrict__ accbuf,
    float* __restrict__ pp, int colblk, int ks, F&& prologue)
{
    const int t = threadIdx.x;
    const int wv = t >> 6, lane = t & 63;
    const float* Wp = W + (size_t)(k0 + wv * RPW) * ldw + wcol0 + lane * 4;
    float4 wreg[RPW];
    #pragma unroll
    for (int i = 0; i < RPW; i++) wreg[i] = *(const float4*)(Wp + (size_t)i * ldw);
    prologue();   // fills xsl; ends with __syncthreads()
    const float4* xs4 = (const float4*)xsl;
    float4 a0 = {0,0,0,0}, a1 = {0,0,0,0}, a2 = {0,0,0,0}, a3 = {0,0,0,0};
    #pragma unroll
    for (int i = 0; i < RPW; i++) {
        float4 w4 = wreg[i];
        float4 xb = xs4[wv * RPW + i];
        a0.x += w4.x * xb.x; a0.y += w4.y * xb.x; a0.z += w4.z * xb.x; a0.w += w4.w * xb.x;
        a1.x += w4.x * xb.y; a1.y += w4.y * xb.y; a1.z += w4.z * xb.y; a1.w += w4.w * xb.y;
        a2.x += w4.x * xb.z; a2.y += w4.y * xb.z; a2.z += w4.z * xb.z; a2.w += w4.w * xb.z;
        a3.x += w4.x * xb.w; a3.y += w4.y * xb.w; a3.z += w4.z * xb.w; a3.w += w4.w * xb.w;
    }
    accbuf[(wv * 64 + lane) * 4 + 0] = a0;
    accbuf[(wv * 64 + lane) * 4 + 1] = a1;
    accbuf[(wv * 64 + lane) * 4 + 2] = a2;
    accbuf[(wv * 64 + lane) * 4 + 3] = a3;
    __syncthreads();
    const int l2 = t >> 2, b2 = t & 3;
    float4 s0 = accbuf[(0 * 64 + l2) * 4 + b2];
    float4 s1 = accbuf[(1 * 64 + l2) * 4 + b2];
    float4 s2 = accbuf[(2 * 64 + l2) * 4 + b2];
    float4 s3 = accbuf[(3 * 64 + l2) * 4 + b2];
    float4 s;
    s.x = s0.x + s1.x + s2.x + s3.x;
    s.y = s0.y + s1.y + s2.y + s3.y;
    s.z = s0.z + s1.z + s2.z + s3.z;
    s.w = s0.w + s1.w + s2.w + s3.w;
    *(float4*)(pp + ((size_t)ks * 4 + b2) * NTOT + colblk * 256 + l2 * 4) = s;
}

// ---------------- qkv GEMV (rmsnorm1-on-read prologue): grid (8, 32) ----------------
__global__ __launch_bounds__(256) void k_qkv(
    const float* __restrict__ h, const float* __restrict__ ssq1,
    const float* __restrict__ ln1,
    const float* __restrict__ Wq, const float* __restrict__ Wk,
    const float* __restrict__ Wv, float* __restrict__ qkvp)
{
    __shared__ float xsl[128];
    __shared__ float4 accbuf[1024];
    const int t = threadIdx.x;
    const int ks = blockIdx.y, k0 = ks * 32, cb = blockIdx.x;
    const float* W; int ldw, wcol0;
    if (cb < 4)      { W = Wq; ldw = 1024; wcol0 = cb * 256; }
    else if (cb < 6) { W = Wk; ldw = 512;  wcol0 = (cb - 4) * 256; }
    else             { W = Wv; ldw = 512;  wcol0 = (cb - 6) * 256; }
    gemv_core<8, 2048>(W, ldw, wcol0, k0, xsl, accbuf, qkvp, cb, ks, [&]() {
        if (t < 128) {
            const int kk = t & 31, b = t >> 5;
            float ssq = 0.f;
            #pragma unroll
            for (int i = 0; i < 8; i++) ssq += ssq1[i * 4 + b];
            const float rms = rsqrtf(ssq * (1.f / 1024.f) + EPS_);
            xsl[kk * 4 + b] = h[b * 1024 + k0 + kk] * rms * ln1[k0 + kk];
        }
        __syncthreads();
    });
}

// ---------------- attention flash chunk (fused KV-cache copy): grid (16 bg, 16 c), block 256 ----------------
__global__ __launch_bounds__(256) void k_attn(
    const float* __restrict__ qkvp,
    const float* __restrict__ qnw, const float* __restrict__ knw,
    const float* __restrict__ kin, const float* __restrict__ vin,
    float* __restrict__ kout, float* __restrict__ vout,
    const int* __restrict__ pos,
    float* __restrict__ opart, float* __restrict__ mlpart)
{
    __shared__ float Kl[33][129];
    __shared__ float Vl[33][129];
    __shared__ float ql[2][128];
    __shared__ float sc[2][36];
    __shared__ float red[8];

    const int t = threadIdx.x;
    const int bg = blockIdx.x, b = bg >> 2, g = bg & 3;
    const int c = blockIdx.y;           // 0..15
    const int lane = t & 63;
    const int r = t >> 7, d = t & 127;
    const float scale = 0.088388347648318447f;  // 1/sqrt(128)

    const float posf = (float)pos[b];
    const int j = d & 63;
    const float invf = exp2f(-(float)j * 0.31143075889569021f);  // 1e6^(-j/64)
    const float ang = posf * invf;
    const float cs = cosf(ang), sn = sinf(ang);
    const int pd = (d < 64) ? d + 64 : d - 64;

    // q: reduce 32 split-K chunks
    float qraw = 0.f;
    {
        const int n = (2 * g + r) * 128 + d;
        #pragma unroll
        for (int cc = 0; cc < 32; cc++) qraw += qkvp[((size_t)cc * 4 + b) * 2048 + n];
    }
    ql[r][d] = qraw;
    float ssq = wave_reduce_sum(qraw * qraw);
    if (lane == 0) red[t >> 6] = ssq;
    __syncthreads();  // (A)
    const float rms_q = rsqrtf((red[r * 2] + red[r * 2 + 1]) * (1.f / 128.f) + EPS_);
    float qv = qraw * rms_q * qnw[d];
    float qp = ql[r][pd] * rms_q * qnw[pd];
    float qro = qv * cs + ((d < 64) ? -qp : qp) * sn;

    // new k/v: only chunk 15
    float kvraw = 0.f;
    if (c == 15) {
        const int base = (t < 128) ? (1024 + g * 128 + d) : (1536 + g * 128 + d);
        #pragma unroll
        for (int cc = 0; cc < 32; cc++) kvraw += qkvp[((size_t)cc * 4 + b) * 2048 + base];
    }
    float kss = wave_reduce_sum((t < 128) ? kvraw * kvraw : 0.f);
    __syncthreads();  // (B)
    ql[r][d] = qro;
    if (lane == 0 && t < 128) red[t >> 6] = kss;
    if (c == 15) { if (t < 128) Kl[32][d] = kvraw; else Vl[32][d] = kvraw; }
    __syncthreads();  // (C)
    float newkv = 0.f;
    if (c == 15) {
        if (t < 128) {
            const float rms_k = rsqrtf((red[0] + red[1]) * (1.f / 128.f) + EPS_);
            float kv_ = Kl[32][d] * rms_k * knw[d];
            float kp  = Kl[32][pd] * rms_k * knw[pd];
            newkv = kv_ * cs + ((d < 64) ? -kp : kp) * sn;
        } else {
            newkv = Vl[32][d];
        }
    }
    __syncthreads();  // (D)
    const size_t out_bg = (size_t)bg * (513 * 128);
    if (c == 15) {
        if (t < 128) { Kl[32][d] = newkv; kout[out_bg + 512 * 128 + d] = newkv; }
        else         { Vl[32][d] = newkv; vout[out_bg + 512 * 128 + d] = newkv; }
    }

    // KV tile (32 keys) load into LDS + copy to output cache (float4)
    const size_t in_bg = (size_t)bg * (512 * 128);
    const int s0 = c * 32;
    #pragma unroll
    for (int i = 0; i < 4; i++) {
        int f4 = i * 256 + t;           // 0..1023 float4s
        int row = f4 >> 5, d0 = (f4 & 31) * 4;
        float4 k4 = *(const float4*)(kin + in_bg + (size_t)(s0 + row) * 128 + d0);
        float4 v4 = *(const float4*)(vin + in_bg + (size_t)(s0 + row) * 128 + d0);
        Kl[row][d0] = k4.x; Kl[row][d0 + 1] = k4.y; Kl[row][d0 + 2] = k4.z; Kl[row][d0 + 3] = k4.w;
        Vl[row][d0] = v4.x; Vl[row][d0 + 1] = v4.y; Vl[row][d0 + 2] = v4.z; Vl[row][d0 + 3] = v4.w;
        *(float4*)(kout + out_bg + (size_t)(s0 + row) * 128 + d0) = k4;
        *(float4*)(vout + out_bg + (size_t)(s0 + row) * 128 + d0) = v4;
    }
    __syncthreads();  // (E)

    // scores
    const int nk = (c == 15) ? 33 : 32;
    const int si = d;
    float sv = -1e30f;
    if (si < nk) {
        float a = 0.f;
        #pragma unroll 8
        for (int dd = 0; dd < 128; dd++) a += ql[r][dd] * Kl[si][dd];
        sv = a * scale;
    }
    float mv = wave_reduce_max(sv);
    if (lane == 0) red[t >> 6] = mv;
    __syncthreads();
    const float m = fmaxf(red[r * 2], red[r * 2 + 1]);
    float p = (si < nk) ? expf(sv - m) : 0.f;
    if (si < nk) sc[r][si] = p;
    float lsum = wave_reduce_sum(p);
    __syncthreads();
    if (lane == 0) red[t >> 6] = lsum;
    __syncthreads();
    const float lr = red[r * 2] + red[r * 2 + 1];
    if (d == 0) {
        mlpart[(size_t)((bg * 2 + r) * 16 + c) * 2 + 0] = m;
        mlpart[(size_t)((bg * 2 + r) * 16 + c) * 2 + 1] = lr;
    }
    float o = 0.f;
    for (int s2 = 0; s2 < nk; s2++) o += sc[r][s2] * Vl[s2][d];
    opart[(size_t)((bg * 2 + r) * 16 + c) * 128 + d] = o;
}

// ---------------- o-proj GEMV (flash-combine prologue): grid (4, 32) ----------------
__global__ __launch_bounds__(256) void k_oproj(
    const float* __restrict__ atto, const float* __restrict__ atml,
    const float* __restrict__ Wo_l, float* __restrict__ opp)
{
    __shared__ float xsl[128];
    __shared__ float4 accbuf[1024];
    const int t = threadIdx.x;
    const int ks = blockIdx.y, k0 = ks * 32, cb = blockIdx.x;
    gemv_core<8, 1024>(Wo_l, 1024, cb * 256, k0, xsl, accbuf, opp, cb, ks, [&]() {
        if (t < 128) {
            const int kk = t & 31, b = t >> 5;
            const int nrow = k0 + kk;
            const int head = nrow >> 7, dh = nrow & 127;
            const int g = head >> 1, rr = head & 1;
            const size_t base = (size_t)((b * 4 + g) * 2 + rr) * 16;
            float mc[16], lc[16], M = -1e30f;
            #pragma unroll
            for (int cc = 0; cc < 16; cc++) {
                mc[cc] = atml[(base + cc) * 2];
                lc[cc] = atml[(base + cc) * 2 + 1];
                M = fmaxf(M, mc[cc]);
            }
            float Ls = 0.f, o = 0.f;
            #pragma unroll
            for (int cc = 0; cc < 16; cc++) {
                float wch = expf(mc[cc] - M);
                Ls += lc[cc] * wch;
                o += atto[(base + cc) * 128 + dh] * wch;
            }
            xsl[kk * 4 + b] = o / Ls;
        }
        __syncthreads();
    });
}

// ---------------- gate/up GEMV (rmsnorm2-on-read prologue): grid (24, 32) ----------------
__global__ __launch_bounds__(256) void k_gateup(
    const float* __restrict__ h, const float* __restrict__ ssq2,
    const float* __restrict__ ln2,
    const float* __restrict__ Wg_l, const float* __restrict__ Wu_l,
    float* __restrict__ gup)
{
    __shared__ float xsl[128];
    __shared__ float4 accbuf[1024];
    const int t = threadIdx.x;
    const int ks = blockIdx.y, k0 = ks * 32, cb = blockIdx.x;
    const float* W; int wcol0;
    if (cb < 12) { W = Wg_l; wcol0 = cb * 256; }
    else         { W = Wu_l; wcol0 = (cb - 12) * 256; }
    gemv_core<8, 6144>(W, 3072, wcol0, k0, xsl, accbuf, gup, cb, ks, [&]() {
        if (t < 128) {
            const int kk = t & 31, b = t >> 5;
            float ssq = 0.f;
            #pragma unroll
            for (int i = 0; i < 8; i++) ssq += ssq2[i * 4 + b];
            const float rms = rsqrtf(ssq * (1.f / 1024.f) + EPS_);
            xsl[kk * 4 + b] = h[b * 1024 + k0 + kk] * rms * ln2[k0 + kk];
        }
        __syncthreads();
    });
}

// ---------------- down GEMV (SiLU prologue): grid (4, 48) x 64 rows = 3072 = I ----------------
__global__ __launch_bounds__(256) void k_down(
    const float* __restrict__ gup, const float* __restrict__ Wd_l,
    float* __restrict__ dwp)
{
    __shared__ float xsl[256];
    __shared__ float4 accbuf[1024];
    const int t = threadIdx.x;
    const int ks = blockIdx.y, k0 = ks * 64, cb = blockIdx.x;
    gemv_core<16, 1024>(Wd_l, 1024, cb * 256, k0, xsl, accbuf, dwp, cb, ks, [&]() {
        const int b = t >> 6, kk = t & 63;
        float gg = 0.f, uu = 0.f;
        #pragma unroll 8
        for (int cc = 0; cc < 32; cc++) {
            gg += gup[((size_t)cc * 4 + b) * 6144 + k0 + kk];
            uu += gup[((size_t)cc * 4 + b) * 6144 + 3072 + k0 + kk];
        }
        xsl[kk * 4 + b] = gg / (1.f + expf(-gg)) * uu;
        __syncthreads();
    });
}

// ---------------- head GEMV (final-norm prologue + past): grid (16, 32) ----------------
__global__ __launch_bounds__(256) void k_head(
    const float* __restrict__ h, const float* __restrict__ ssq1,
    const float* __restrict__ normw, const float* __restrict__ headw,
    float* __restrict__ hdp, float* __restrict__ past)
{
    __shared__ float xsl[128];
    __shared__ float4 accbuf[1024];
    const int t = threadIdx.x;
    const int ks = blockIdx.y, k0 = ks * 32, cb = blockIdx.x;
    gemv_core<8, 4096>(headw, 4096, cb * 256, k0, xsl, accbuf, hdp, cb, ks, [&]() {
        if (t < 128) {
            const int kk = t & 31, b = t >> 5;
            float ssq = 0.f;
            #pragma unroll
            for (int i = 0; i < 8; i++) ssq += ssq1[i * 4 + b];
            const float rms = rsqrtf(ssq * (1.f / 1024.f) + EPS_);
            float x = h[b * 1024 + k0 + kk] * rms * normw[k0 + kk];
            xsl[kk * 4 + b] = x;
            if (cb == 0) past[b * 1024 + k0 + kk] = x;
        }
        __syncthreads();
    });
}

// ---------------- logits reduce: grid 16 ----------------
__global__ __launch_bounds__(256) void k_logits(
    const float* __restrict__ hdp, float* __restrict__ logits)
{
    int t4 = blockIdx.x * 256 + threadIdx.x;   // 0..4095 float4s
    int b = t4 >> 10, n4 = t4 & 1023;
    float4 s = {0.f, 0.f, 0.f, 0.f};
    #pragma unroll
    for (int c = 0; c < 32; c++) {
        float4 v = *(const float4*)(hdp + ((size_t)c * 4 + b) * 4096 + n4 * 4);
        s.x += v.x; s.y += v.y; s.z += v.z; s.w += v.w;
    }
    *(float4*)(logits + (size_t)b * 4096 + n4 * 4) = s;
}

extern "C" void kernel_launch(void* const* d_in, const int* in_sizes, int n_in,
                              void* d_out, int out_size, void* d_ws, size_t ws_size,
                              hipStream_t stream)
{
    const int*   cb0   = (const int*)d_in[0];
    const int*   cb1   = (const int*)d_in[1];
    const float* trail = (const float*)d_in[2];
    const float* kvin  = (const float*)d_in[3];
    const int*   pos   = (const int*)d_in[4];
    const float* cb0e  = (const float*)d_in[5];
    const float* cpe   = (const float*)d_in[6];
    const float* Wq    = (const float*)d_in[7];
    const float* Wk    = (const float*)d_in[8];
    const float* Wv    = (const float*)d_in[9];
    const float* Wo    = (const float*)d_in[10];
    const float* qnw   = (const float*)d_in[11];
    const float* knw   = (const float*)d_in[12];
    const float* ln1   = (const float*)d_in[13];
    const float* ln2   = (const float*)d_in[14];
    const float* Wg    = (const float*)d_in[15];
    const float* Wu    = (const float*)d_in[16];
    const float* Wd    = (const float*)d_in[17];
    const float* normw = (const float*)d_in[18];
    const float* headw = (const float*)d_in[19];

    float* out    = (float*)d_out;
    float* logits = out;
    float* kvout  = out + 16384;
    float* past   = out + 16384 + (size_t)2 * L_ * B_ * KVH_ * (S_ + 1) * HD_;
    float* ws = (float*)d_ws;

    float* h    = ws + WS_H;
    float* ssq1 = ws + WS_SSQ1;
    float* ssq2 = ws + WS_SSQ2;
    float* qkvp = ws + WS_QKVP;
    float* atto = ws + WS_ATTO;
    float* atml = ws + WS_ATML;
    float* opp  = ws + WS_OPP;
    float* gup  = ws + WS_GUP;
    float* dwp  = ws + WS_DWP;
    float* hdp  = ws + WS_HDP;

    const size_t IN_PLANE  = (size_t)B_ * KVH_ * S_ * HD_;
    const size_t OUT_PLANE = (size_t)B_ * KVH_ * (S_ + 1) * HD_;

    k_embed<<<32, 128, 0, stream>>>(cb0, cb1, trail, cb0e, cpe, h, ssq1);

    for (int l = 0; l < L_; l++) {
        k_qkv<<<dim3(8, 32), 256, 0, stream>>>(
            h, ssq1, ln1 + (size_t)l * H_,
            Wq + (size_t)l * H_ * 1024, Wk + (size_t)l * H_ * 512,
            Wv + (size_t)l * H_ * 512, qkvp);
        k_attn<<<dim3(16, 16), 256, 0, stream>>>(
            qkvp, qnw + (size_t)l * HD_, knw + (size_t)l * HD_,
            kvin + (size_t)(2 * l) * IN_PLANE, kvin + (size_t)(2 * l + 1) * IN_PLANE,
            kvout + (size_t)(2 * l) * OUT_PLANE, kvout + (size_t)(2 * l + 1) * OUT_PLANE,
            pos, atto, atml);
        k_oproj<<<dim3(4, 32), 256, 0, stream>>>(
            atto, atml, Wo + (size_t)l * 1024 * H_, opp);
        k_norm<32><<<32, 256, 0, stream>>>(opp, h, ssq2);
        k_gateup<<<dim3(24, 32), 256, 0, stream>>>(
            h, ssq2, ln2 + (size_t)l * H_,
            Wg + (size_t)l * H_ * I_, Wu + (size_t)l * H_ * I_, gup);
        k_down<<<dim3(4, 48), 256, 0, stream>>>(
            gup, Wd + (size_t)l * I_ * H_, dwp);
        k_norm<48><<<32, 256, 0, stream>>>(dwp, h, ssq1);
    }
    k_head<<<dim3(16, 32), 256, 0, stream>>>(h, ssq1, normw, headw, hdp, past);
    k_logits<<<16, 256, 0, stream>>>(hdp, logits);
}